// Round 1
// baseline (1248.968 us; speedup 1.0000x reference)
//
#include <hip/hip_runtime.h>
#include <hip/hip_bf16.h>
#include <stdint.h>

// Neural-ODE via Kutta RK3 (h=1), bf16 MFMA GEMMs. State y fp32, operands
// bf16, accum fp32. RK3 numerics identical to R6 (absmax 0.05078, passing).
// R7: GEMM ported from m97 128^2 2-barrier structure (~690 TF on these
// shapes; MfmaUtil 28%) to the 256^2 8-phase pipelined schedule:
//   - 8 waves (2Mx4N), acc[8][4], BK=64, 128 KiB LDS (2 parities).
//   - register-pipelined ds_reads: Q0 frags of tile t+1 read in phase 3 of
//     tile t (12-read phase); B-nj1 at p=0; A-mi1 at p=1; p=2 reads nothing.
//     This frees each LDS region early enough that staging 2 tiles ahead
//     into the SAME parity is race-free (every overwrite is preceded by a
//     lgkmcnt(0)-confirmed last read + barrier).
//   - staging order per tile: A0(p0),B0(p1),B1(p2),A1(p3), 2xGLD16 each,
//     targeting tile t+2; single vmcnt(6) per K-tile at p=3 (3 half-tiles
//     in flight, never drain to 0 in the loop); raw s_barrier throughout.
//   - T5 setprio(1) around MFMA clusters; rule-18 sched_barrier(0) after
//     each inline lgkmcnt(0); XOR granule swizzle (bank-conflict 0);
//     bijective XCD block swizzle (nwg%8==0 for all shapes here).

#define BM 256
#define BN 256
#define BK 64

typedef __attribute__((ext_vector_type(4))) float floatx4;
typedef __attribute__((ext_vector_type(8))) short short8x;

__device__ __forceinline__ short f2bf(float f) {
  unsigned u = __builtin_bit_cast(unsigned, f);
  unsigned r = (u + 0x7fffu + ((u >> 16) & 1u)) >> 16;  // RNE
  return (short)r;
}

#define GLD16(gp, lp)                                                          \
  __builtin_amdgcn_global_load_lds(                                            \
      (const __attribute__((address_space(1))) void*)(gp),                     \
      (__attribute__((address_space(3))) void*)(lp), 16, 0, 0)

#define BAR() __builtin_amdgcn_s_barrier()
#define SP1() __builtin_amdgcn_s_setprio(1)
#define SP0() __builtin_amdgcn_s_setprio(0)
#define LGKM0()                                                                \
  do {                                                                         \
    asm volatile("s_waitcnt lgkmcnt(0)" ::: "memory");                         \
    __builtin_amdgcn_sched_barrier(0);                                         \
  } while (0)
#define VMC(n) asm volatile("s_waitcnt vmcnt(" #n ")" ::: "memory")

// C[M,N] = A[M,K](bf16) * Bt[N,K]^T(bf16) + bias, per-mode epilogue (RK3):
//  mode 0: Cb = bf16(relu(v))
//  mode 1: acc = v;           ytbf = bf16(y + 0.5*v)     (k1)
//  mode 2: a=acc; acc=a+4v;   ytbf = bf16(y - a + 2*v)   (k2)
//  mode 3: yout = y + (acc+v)/6                          (k3/update)
__global__ __launch_bounds__(512, 2) void gemm8p(
    const short* __restrict__ A, const short* __restrict__ Bt,
    const float* __restrict__ bias, short* __restrict__ Cb,
    float* __restrict__ accbuf, const float* __restrict__ y,
    float* __restrict__ yout, short* __restrict__ ytbf,
    int M, int N, int K, int mode) {
  __shared__ __align__(16) short As[2][BM * BK];
  __shared__ __align__(16) short Bs[2][BN * BK];

  const int tid = threadIdx.x;
  const int lane = tid & 63;
  const int quad = lane >> 4;
  const int l15 = lane & 15;
  const int l7 = lane & 7;
  const int wid = tid >> 6;
  const int wm = (wid >> 2) * 128;  // wave M offset (2 wave-rows)
  const int wn = (wid & 3) * 64;    // wave N offset (4 wave-cols)

  // XCD-aware chunked block swizzle (bijective: nwg % 8 == 0 here: 256/128)
  const int gx = gridDim.x;
  const int nwg = gx * gridDim.y;
  const int bid = blockIdx.y * gx + blockIdx.x;
  const int sb = (bid & 7) * (nwg >> 3) + (bid >> 3);
  const int tile_m = (sb / gx) * BM;
  const int tile_n = (sb % gx) * BN;

  // ---- staging geometry: XOR-swizzled global source, linear LDS dest ----
  // LDS slot granule g of row r holds global granule g ^ (r & 7).
  const int t8 = tid >> 3;
  const int gsg = (tid & 7) ^ (t8 & 7);
  const short* Ag = A + (size_t)(tile_m + t8) * K + gsg * 8;
  const short* Bg =
      Bt + (size_t)(tile_n + (t8 >> 5) * 64 + (t8 & 31)) * K + gsg * 8;
  const int a_l0 = tid * 8;  // short-index LDS offsets (linear per wave)
  const int b_l0 = ((t8 >> 5) * 64 + (t8 & 31)) * 64 + (tid & 7) * 8;

  // A-half h = rows [h*64,h*64+64) u [128+h*64, ...): the mi-half read set.
#define STG_A(P, h, ko)                                                        \
  do {                                                                         \
    GLD16(Ag + (size_t)((h) * 64) * K + (ko), &As[P][a_l0 + (h) * 64 * 64]);   \
    GLD16(Ag + (size_t)(128 + (h) * 64) * K + (ko),                            \
          &As[P][a_l0 + (128 + (h) * 64) * 64]);                               \
  } while (0)
  // B-half h = rows {q*64 + h*32 .. +31}, q=0..3: the nj-half read set.
#define STG_B(P, h, ko)                                                        \
  do {                                                                         \
    GLD16(Bg + (size_t)((h) * 32) * K + (ko), &Bs[P][b_l0 + (h) * 32 * 64]);   \
    GLD16(Bg + (size_t)(128 + (h) * 32) * K + (ko),                            \
          &Bs[P][b_l0 + (128 + (h) * 32) * 64]);                               \
  } while (0)

  // ---- fragment read bases (undo XOR swizzle; row&7 == l7 everywhere) ----
  const int ar0 = (wm + l15) * 64 + ((quad) ^ l7) * 8;      // kk=0
  const int ar1 = (wm + l15) * 64 + ((4 + quad) ^ l7) * 8;  // kk=1
  const int br0 = (wn + l15) * 64 + ((quad) ^ l7) * 8;
  const int br1 = (wn + l15) * 64 + ((4 + quad) ^ l7) * 8;

#define RD_A(dst, P, mih)                                                      \
  do {                                                                         \
    _Pragma("unroll") for (int i = 0; i < 4; ++i) {                            \
      dst[i][0] = *(const short8x*)&As[P][ar0 + (mih) * 4096 + i * 1024];      \
      dst[i][1] = *(const short8x*)&As[P][ar1 + (mih) * 4096 + i * 1024];      \
    }                                                                          \
  } while (0)
#define RD_B(dst, P, njh)                                                      \
  do {                                                                         \
    _Pragma("unroll") for (int j = 0; j < 2; ++j) {                            \
      dst[j][0] = *(const short8x*)&Bs[P][br0 + (njh) * 2048 + j * 1024];      \
      dst[j][1] = *(const short8x*)&Bs[P][br1 + (njh) * 2048 + j * 1024];      \
    }                                                                          \
  } while (0)

  floatx4 acc[8][4];
#pragma unroll
  for (int i = 0; i < 8; ++i)
#pragma unroll
    for (int j = 0; j < 4; ++j) acc[i][j] = (floatx4){0.f, 0.f, 0.f, 0.f};

  short8x a0[4][2], a1[4][2], b0[2][2], b1[2][2];

#define MMQ(af, bf, mi0, nj0)                                                  \
  do {                                                                         \
    _Pragma("unroll") for (int i = 0; i < 4; ++i) {                            \
      _Pragma("unroll") for (int j = 0; j < 2; ++j) {                          \
        acc[(mi0) + i][(nj0) + j] = __builtin_amdgcn_mfma_f32_16x16x32_bf16(   \
            af[i][0], bf[j][0], acc[(mi0) + i][(nj0) + j], 0, 0, 0);           \
        acc[(mi0) + i][(nj0) + j] = __builtin_amdgcn_mfma_f32_16x16x32_bf16(   \
            af[i][1], bf[j][1], acc[(mi0) + i][(nj0) + j], 0, 0, 0);           \
      }                                                                        \
    }                                                                          \
  } while (0)

  const int nk = K / BK;
  int ko;

  // ---- prologue: stage K-tiles 0,1; read tile-0 Q0 fragments ----
  STG_A(0, 0, 0);
  STG_B(0, 0, 0);
  STG_B(0, 1, 0);
  STG_A(0, 1, 0);
  STG_A(1, 0, 64);
  STG_B(1, 0, 64);
  STG_B(1, 1, 64);
  STG_A(1, 1, 64);
  VMC(8);  // tile 0 landed; tile 1's 8 loads still in flight
  BAR();
  RD_A(a0, 0, 0);
  RD_B(b0, 0, 0);
  LGKM0();
  BAR();
  ko = 128;  // k-offset (shorts) of next tile to stage (= tile 2)

  // Steady tile at parity P: compute tile t from buf P, stage tile t+2 into
  // buf P (regions free: A0/B0 last read at p=3 of t-1, B1 at p=0, A1 at
  // p=1 -- each confirmed by lgkmcnt(0)+barrier before the staging issue),
  // read tile t+1's Q0 frags at p=3 from buf P^1 (vmcnt(6) confirms all of
  // tile t+1 landed; t+2's A0,B0,B1 remain in flight).
#define TILE_STEADY(P)                                                         \
  do {                                                                         \
    /* p=0: Q0 = a0 x b0 */                                                    \
    RD_B(b1, P, 1);                                                            \
    STG_A(P, 0, ko);                                                           \
    BAR();                                                                     \
    LGKM0();                                                                   \
    SP1();                                                                     \
    MMQ(a0, b0, 0, 0);                                                         \
    SP0();                                                                     \
    BAR();                                                                     \
    /* p=1: Q1 = a0 x b1 */                                                    \
    RD_A(a1, P, 1);                                                            \
    STG_B(P, 0, ko);                                                           \
    BAR();                                                                     \
    LGKM0();                                                                   \
    SP1();                                                                     \
    MMQ(a0, b1, 0, 2);                                                         \
    SP0();                                                                     \
    BAR();                                                                     \
    /* p=2: Q2 = a1 x b0 (no ds_reads this phase) */                           \
    STG_B(P, 1, ko);                                                           \
    BAR();                                                                     \
    SP1();                                                                     \
    MMQ(a1, b0, 4, 0);                                                         \
    SP0();                                                                     \
    BAR();                                                                     \
    /* p=3: Q3 = a1 x b1; prefetch next tile's Q0 frags (12 reads) */          \
    VMC(6);                                                                    \
    RD_A(a0, (P) ^ 1, 0);                                                      \
    RD_B(b0, (P) ^ 1, 0);                                                      \
    STG_A(P, 1, ko);                                                           \
    BAR();                                                                     \
    LGKM0();                                                                   \
    SP1();                                                                     \
    MMQ(a1, b1, 4, 2);                                                         \
    SP0();                                                                     \
    BAR();                                                                     \
    ko += 64;                                                                  \
  } while (0)

  // tau = nk-2: no staging; vmcnt(0) before reading last tile's frags.
#define TILE_TAIL1(P)                                                          \
  do {                                                                         \
    RD_B(b1, P, 1);                                                            \
    BAR();                                                                     \
    LGKM0();                                                                   \
    SP1();                                                                     \
    MMQ(a0, b0, 0, 0);                                                         \
    SP0();                                                                     \
    BAR();                                                                     \
    RD_A(a1, P, 1);                                                            \
    BAR();                                                                     \
    LGKM0();                                                                   \
    SP1();                                                                     \
    MMQ(a0, b1, 0, 2);                                                         \
    SP0();                                                                     \
    BAR();                                                                     \
    BAR();                                                                     \
    SP1();                                                                     \
    MMQ(a1, b0, 4, 0);                                                         \
    SP0();                                                                     \
    BAR();                                                                     \
    VMC(0);                                                                    \
    RD_A(a0, (P) ^ 1, 0);                                                      \
    RD_B(b0, (P) ^ 1, 0);                                                      \
    BAR();                                                                     \
    LGKM0();                                                                   \
    SP1();                                                                     \
    MMQ(a1, b1, 4, 2);                                                         \
    SP0();                                                                     \
    BAR();                                                                     \
  } while (0)

  // tau = nk-1: last tile, no cross-wave LDS hazards remain.
#define TILE_TAIL2(P)                                                          \
  do {                                                                         \
    RD_B(b1, P, 1);                                                            \
    LGKM0();                                                                   \
    SP1();                                                                     \
    MMQ(a0, b0, 0, 0);                                                         \
    SP0();                                                                     \
    RD_A(a1, P, 1);                                                            \
    LGKM0();                                                                   \
    SP1();                                                                     \
    MMQ(a0, b1, 0, 2);                                                         \
    SP0();                                                                     \
    SP1();                                                                     \
    MMQ(a1, b0, 4, 0);                                                         \
    SP0();                                                                     \
    SP1();                                                                     \
    MMQ(a1, b1, 4, 2);                                                         \
    SP0();                                                                     \
  } while (0)

  for (int it = 0; it < (nk - 2) / 2; ++it) {
    TILE_STEADY(0);
    TILE_STEADY(1);
  }
  TILE_TAIL1(0);
  TILE_TAIL2(1);

  // ---- epilogue. C/D layout: col = lane&15, row = quad*4 + reg ----
  // acc[m][n]: row offset = wm + m*16 (+quad*4+r), col offset = wn + n*16.
#pragma unroll
  for (int n = 0; n < 4; ++n) {
    const int col = tile_n + wn + n * 16 + l15;
    const float bv = bias[col];
#pragma unroll
    for (int m = 0; m < 8; ++m) {
      const int row0 = tile_m + wm + m * 16 + quad * 4;
#pragma unroll
      for (int r = 0; r < 4; ++r) {
        const size_t idx = (size_t)(row0 + r) * N + col;
        float v = acc[m][n][r] + bv;
        if (mode == 0) {
          v = v > 0.f ? v : 0.f;
          Cb[idx] = f2bf(v);
        } else if (mode == 1) {
          accbuf[idx] = v;
          ytbf[idx] = f2bf(y[idx] + 0.5f * v);
        } else if (mode == 2) {
          float a = accbuf[idx];
          accbuf[idx] = a + 4.f * v;
          ytbf[idx] = f2bf(y[idx] - a + 2.f * v);
        } else {
          yout[idx] = y[idx] + (1.f / 6.f) * (accbuf[idx] + v);
        }
      }
    }
  }
  (void)M;
}

// W[K][N] fp32 -> Wt[N][K] bf16 (B^T layout)
__global__ __launch_bounds__(256) void transpose_bf16(
    const float* __restrict__ W, short* __restrict__ Wt, int K, int N) {
  __shared__ float t[32][33];
  int tx = threadIdx.x & 31, ty = threadIdx.x >> 5;
  int k0 = blockIdx.y * 32, n0 = blockIdx.x * 32;
#pragma unroll
  for (int r = 0; r < 32; r += 8)
    t[ty + r][tx] = W[(size_t)(k0 + ty + r) * N + (n0 + tx)];
  __syncthreads();
#pragma unroll
  for (int r = 0; r < 32; r += 8)
    Wt[(size_t)(n0 + ty + r) * K + (k0 + tx)] = f2bf(t[tx][ty + r]);
}

__global__ __launch_bounds__(256) void init_y_kernel(
    const float* __restrict__ x, float* __restrict__ y,
    short* __restrict__ ybf, int n4) {
  int i = blockIdx.x * 256 + threadIdx.x;
  if (i >= n4) return;
  float4 v = ((const float4*)x)[i];
  ((float4*)y)[i] = v;
  short4 b;
  b.x = f2bf(v.x);
  b.y = f2bf(v.y);
  b.z = f2bf(v.z);
  b.w = f2bf(v.w);
  ((short4*)ybf)[i] = b;
}

extern "C" void kernel_launch(void* const* d_in, const int* in_sizes, int n_in,
                              void* d_out, int out_size, void* d_ws,
                              size_t ws_size, hipStream_t stream) {
  const float* x = (const float*)d_in[0];
  const float* W1 = (const float*)d_in[1];
  const float* b1 = (const float*)d_in[2];
  const float* W2 = (const float*)d_in[3];
  const float* b2 = (const float*)d_in[4];
  const float* W3 = (const float*)d_in[5];
  const float* b3 = (const float*)d_in[6];

  const int B = 8192, D = 1024, H = 2048;
  char* ws = (char*)d_ws;
  short* W1t = (short*)(ws + (0ull << 20));   // [H,D] bf16   4 MB
  short* W2t = (short*)(ws + (4ull << 20));   // [H,H] bf16   8 MB
  short* W3t = (short*)(ws + (12ull << 20));  // [D,H] bf16   4 MB
  short* ybf = (short*)(ws + (16ull << 20));  // [B,D] bf16  16 MB
  short* h1 = (short*)(ws + (32ull << 20));   // [B,H] bf16  32 MB
  short* h2 = (short*)(ws + (64ull << 20));   // [B,H] bf16  32 MB
  float* acc = (float*)(ws + (96ull << 20));  // [B,D] f32   32 MB
  float* y = (float*)(ws + (128ull << 20));   // [B,D] f32   32 MB
  float* out = (float*)d_out;

  transpose_bf16<<<dim3(H / 32, D / 32), 256, 0, stream>>>(W1, W1t, D, H);
  transpose_bf16<<<dim3(H / 32, H / 32), 256, 0, stream>>>(W2, W2t, H, H);
  transpose_bf16<<<dim3(D / 32, H / 32), 256, 0, stream>>>(W3, W3t, H, D);
  init_y_kernel<<<(B * D / 4 + 255) / 256, 256, 0, stream>>>(x, y, ybf,
                                                             B * D / 4);

  // Kutta RK3, single step h=1: stages mode 1, 2, 3.
  for (int stg = 1; stg <= 3; ++stg) {
    // layer 1: h1 = relu(ybf @ W1 + b1)   [8192,2048] K=1024, 256 blocks
    gemm8p<<<dim3(H / BN, B / BM), 512, 0, stream>>>(
        ybf, W1t, b1, h1, nullptr, nullptr, nullptr, nullptr, B, H, D, 0);
    // layer 2: h2 = relu(h1 @ W2 + b2)    [8192,2048] K=2048, 256 blocks
    gemm8p<<<dim3(H / BN, B / BM), 512, 0, stream>>>(
        h1, W2t, b2, h2, nullptr, nullptr, nullptr, nullptr, B, H, H, 0);
    // layer 3 + RK3 stage epilogue        [8192,1024] K=2048, 128 blocks
    gemm8p<<<dim3(D / BN, B / BM), 512, 0, stream>>>(
        h2, W3t, b3, nullptr, acc, y, (stg == 3) ? out : nullptr, ybf, B, D,
        H, stg);
  }
}

// Round 2
// 906.150 us; speedup vs baseline: 1.3783x; 1.3783x over previous
//
#include <hip/hip_runtime.h>
#include <hip/hip_bf16.h>
#include <stdint.h>

// Neural-ODE via Kutta RK3 (h=1), bf16 MFMA GEMMs. State y fp32, operands
// bf16, accum fp32. RK3 numerics identical to R6 (absmax 0.05078, passing).
// R8: fix R7's 8-phase regression (1249us, MfmaUtil 8%, +36MB scratch
// writes). Three changes, all toward the verified m201 template:
//  1. Z-order quadrants Q0(a*b0) Q1(a*b1) Q2(a'*b1) Q3(a'*b0): A-frag slot
//     reloaded mid-tile -> max live frags 64 VGPR (was 96) + 128 AGPR acc
//     => no spill at the 256-reg/wave budget (R7 was at the edge; scratch
//     traffic was the stall).
//  2. Template-exact waits: plain `s_waitcnt lgkmcnt(0)` asm after each
//     leading barrier -- NO "memory" clobber, NO sched_barrier (rule 18
//     applies only to asm ds_reads; ours are C++ loads). R7's 8x/tile
//     pinning was m141's failure mode.
//  3. Race-free DMA confirm: single vmcnt(8) per K-tile placed BEFORE the
//     p3 trailing barrier (VMC -> BAR -> read), keeping 8 loads in flight
//     at all times (counted-vmcnt, never drain; m218's T4 lever). R7's
//     VMC(6)-then-read had no barrier between confirm and cross-wave read.
// Staging (tile t+2, same parity): p1: A0+B0, p2: B1, p3: A1 -- each region
// freed by the preceding phase's lgkm-confirmed reads + trailing barrier.

#define BM 256
#define BN 256
#define BK 64

typedef __attribute__((ext_vector_type(4))) float floatx4;
typedef __attribute__((ext_vector_type(8))) short short8x;

__device__ __forceinline__ short f2bf(float f) {
  unsigned u = __builtin_bit_cast(unsigned, f);
  unsigned r = (u + 0x7fffu + ((u >> 16) & 1u)) >> 16;  // RNE
  return (short)r;
}

#define GLD16(gp, lp)                                                          \
  __builtin_amdgcn_global_load_lds(                                            \
      (const __attribute__((address_space(1))) void*)(gp),                     \
      (__attribute__((address_space(3))) void*)(lp), 16, 0, 0)

#define BAR() __builtin_amdgcn_s_barrier()
#define SP1() __builtin_amdgcn_s_setprio(1)
#define SP0() __builtin_amdgcn_s_setprio(0)
#define LG0() asm volatile("s_waitcnt lgkmcnt(0)")
#define VMC(n) asm volatile("s_waitcnt vmcnt(" #n ")" ::: "memory")

// C[M,N] = A[M,K](bf16) * Bt[N,K]^T(bf16) + bias, per-mode epilogue (RK3):
//  mode 0: Cb = bf16(relu(v))
//  mode 1: acc = v;           ytbf = bf16(y + 0.5*v)     (k1)
//  mode 2: a=acc; acc=a+4v;   ytbf = bf16(y - a + 2*v)   (k2)
//  mode 3: yout = y + (acc+v)/6                          (k3/update)
__global__ __launch_bounds__(512, 2) void gemm8p(
    const short* __restrict__ A, const short* __restrict__ Bt,
    const float* __restrict__ bias, short* __restrict__ Cb,
    float* __restrict__ accbuf, const float* __restrict__ y,
    float* __restrict__ yout, short* __restrict__ ytbf,
    int M, int N, int K, int mode) {
  __shared__ __align__(16) short As[2][BM * BK];
  __shared__ __align__(16) short Bs[2][BN * BK];

  const int tid = threadIdx.x;
  const int lane = tid & 63;
  const int quad = lane >> 4;
  const int l15 = lane & 15;
  const int l7 = lane & 7;
  const int wid = tid >> 6;
  const int wm = (wid >> 2) * 128;  // wave M offset (2 wave-rows)
  const int wn = (wid & 3) * 64;    // wave N offset (4 wave-cols)

  // XCD-aware chunked block swizzle (bijective: nwg % 8 == 0 here: 256/128)
  const int gx = gridDim.x;
  const int nwg = gx * gridDim.y;
  const int bid = blockIdx.y * gx + blockIdx.x;
  const int sb = (bid & 7) * (nwg >> 3) + (bid >> 3);
  const int tile_m = (sb / gx) * BM;
  const int tile_n = (sb % gx) * BN;

  // ---- staging geometry: XOR-swizzled global source, linear LDS dest ----
  // LDS slot granule g of row r holds global granule g ^ (r & 7).
  const int t8 = tid >> 3;
  const int gsg = (tid & 7) ^ (t8 & 7);
  const short* Ag = A + (size_t)(tile_m + t8) * K + gsg * 8;
  const short* Bg =
      Bt + (size_t)(tile_n + (t8 >> 5) * 64 + (t8 & 31)) * K + gsg * 8;
  const int a_l0 = tid * 8;  // short-index LDS offsets (linear per wave)
  const int b_l0 = ((t8 >> 5) * 64 + (t8 & 31)) * 64 + (tid & 7) * 8;

  // A-half h = rows [h*64,h*64+64) u [128+h*64, ...): the mi-half read set.
#define STG_A(P, h, ko)                                                        \
  do {                                                                         \
    GLD16(Ag + (size_t)((h) * 64) * K + (ko), &As[P][a_l0 + (h) * 64 * 64]);   \
    GLD16(Ag + (size_t)(128 + (h) * 64) * K + (ko),                            \
          &As[P][a_l0 + (128 + (h) * 64) * 64]);                               \
  } while (0)
  // B-half h = rows {q*64 + h*32 .. +31}, q=0..3: the nj-half read set.
#define STG_B(P, h, ko)                                                        \
  do {                                                                         \
    GLD16(Bg + (size_t)((h) * 32) * K + (ko), &Bs[P][b_l0 + (h) * 32 * 64]);   \
    GLD16(Bg + (size_t)(128 + (h) * 32) * K + (ko),                            \
          &Bs[P][b_l0 + (128 + (h) * 32) * 64]);                               \
  } while (0)

  // ---- fragment read bases (undo XOR swizzle; row&7 == l7 everywhere) ----
  const int ar0 = (wm + l15) * 64 + ((quad) ^ l7) * 8;      // kk=0
  const int ar1 = (wm + l15) * 64 + ((4 + quad) ^ l7) * 8;  // kk=1
  const int br0 = (wn + l15) * 64 + ((quad) ^ l7) * 8;
  const int br1 = (wn + l15) * 64 + ((4 + quad) ^ l7) * 8;

#define RD_A(dst, P, mih)                                                      \
  do {                                                                         \
    _Pragma("unroll") for (int i = 0; i < 4; ++i) {                            \
      dst[i][0] = *(const short8x*)&As[P][ar0 + (mih) * 4096 + i * 1024];      \
      dst[i][1] = *(const short8x*)&As[P][ar1 + (mih) * 4096 + i * 1024];      \
    }                                                                          \
  } while (0)
#define RD_B(dst, P, njh)                                                      \
  do {                                                                         \
    _Pragma("unroll") for (int j = 0; j < 2; ++j) {                            \
      dst[j][0] = *(const short8x*)&Bs[P][br0 + (njh) * 2048 + j * 1024];      \
      dst[j][1] = *(const short8x*)&Bs[P][br1 + (njh) * 2048 + j * 1024];      \
    }                                                                          \
  } while (0)

  floatx4 acc[8][4];
#pragma unroll
  for (int i = 0; i < 8; ++i)
#pragma unroll
    for (int j = 0; j < 4; ++j) acc[i][j] = (floatx4){0.f, 0.f, 0.f, 0.f};

  // Z-order frag residency: a[] reused for lo/hi halves; b0 lives all tile.
  short8x a[4][2], b0[2][2], b1[2][2];

#define MMQ(af, bf, mi0, nj0)                                                  \
  do {                                                                         \
    _Pragma("unroll") for (int i = 0; i < 4; ++i) {                            \
      _Pragma("unroll") for (int j = 0; j < 2; ++j) {                          \
        acc[(mi0) + i][(nj0) + j] = __builtin_amdgcn_mfma_f32_16x16x32_bf16(   \
            af[i][0], bf[j][0], acc[(mi0) + i][(nj0) + j], 0, 0, 0);           \
        acc[(mi0) + i][(nj0) + j] = __builtin_amdgcn_mfma_f32_16x16x32_bf16(   \
            af[i][1], bf[j][1], acc[(mi0) + i][(nj0) + j], 0, 0, 0);           \
      }                                                                        \
    }                                                                          \
  } while (0)

  const int nk = K / BK;
  int ko;

  // ---- prologue: stage K-tiles 0 (parity 0) and 1 (parity 1) ----
  STG_A(0, 0, 0);
  STG_B(0, 0, 0);
  STG_B(0, 1, 0);
  STG_A(0, 1, 0);
  STG_A(1, 0, 64);
  STG_B(1, 0, 64);
  STG_B(1, 1, 64);
  STG_A(1, 1, 64);
  VMC(8);  // tile 0's 8 loads landed; tile 1's 8 remain in flight
  BAR();
  ko = 128;  // k-offset (shorts) of next tile to stage (= tile 2)

  // Steady tile at parity P: compute tile t from buf P (Z-order quadrants),
  // stage tile t+2 into buf P. Region frees: A0/B0 after p0's confirmed
  // reads (stage at p1), B1 after p1 (stage at p2), A1 after p2 (stage at
  // p3). Single vmcnt(8) per tile at p3 BEFORE the trailing barrier:
  // confirms tile t+1 fully landed across all waves, leaves t+2's 8 loads
  // in flight. Never drains to 0 in the main loop.
#define TILE_STEADY(P)                                                         \
  do {                                                                         \
    /* p0: Q0 = a(lo) x b0 */                                                  \
    RD_A(a, P, 0);                                                             \
    RD_B(b0, P, 0);                                                            \
    BAR();                                                                     \
    LG0();                                                                     \
    SP1();                                                                     \
    MMQ(a, b0, 0, 0);                                                          \
    SP0();                                                                     \
    BAR();                                                                     \
    /* p1: Q1 = a(lo) x b1 ; stage A0,B0 of t+2 */                             \
    RD_B(b1, P, 1);                                                            \
    STG_A(P, 0, ko);                                                           \
    STG_B(P, 0, ko);                                                           \
    BAR();                                                                     \
    LG0();                                                                     \
    SP1();                                                                     \
    MMQ(a, b1, 0, 2);                                                          \
    SP0();                                                                     \
    BAR();                                                                     \
    /* p2: Q2 = a(hi) x b1 ; stage B1 */                                       \
    RD_A(a, P, 1);                                                             \
    STG_B(P, 1, ko);                                                           \
    BAR();                                                                     \
    LG0();                                                                     \
    SP1();                                                                     \
    MMQ(a, b1, 4, 2);                                                          \
    SP0();                                                                     \
    BAR();                                                                     \
    /* p3: Q3 = a(hi) x b0 ; stage A1 ; tile-boundary vmcnt+barrier */         \
    STG_A(P, 1, ko);                                                           \
    BAR();                                                                     \
    SP1();                                                                     \
    MMQ(a, b0, 4, 0);                                                          \
    SP0();                                                                     \
    VMC(8);                                                                    \
    BAR();                                                                     \
    ko += 64;                                                                  \
  } while (0)

  // tile nk-2: no staging; vmcnt(0)+barrier confirms the last tile.
#define TILE_TAIL1(P)                                                          \
  do {                                                                         \
    RD_A(a, P, 0);                                                             \
    RD_B(b0, P, 0);                                                            \
    BAR();                                                                     \
    LG0();                                                                     \
    SP1();                                                                     \
    MMQ(a, b0, 0, 0);                                                          \
    SP0();                                                                     \
    BAR();                                                                     \
    RD_B(b1, P, 1);                                                            \
    BAR();                                                                     \
    LG0();                                                                     \
    SP1();                                                                     \
    MMQ(a, b1, 0, 2);                                                          \
    SP0();                                                                     \
    BAR();                                                                     \
    RD_A(a, P, 1);                                                             \
    BAR();                                                                     \
    LG0();                                                                     \
    SP1();                                                                     \
    MMQ(a, b1, 4, 2);                                                          \
    SP0();                                                                     \
    BAR();                                                                     \
    SP1();                                                                     \
    MMQ(a, b0, 4, 0);                                                          \
    SP0();                                                                     \
    VMC(0);                                                                    \
    BAR();                                                                     \
  } while (0)

  // tile nk-1: last tile, no staging/vmcnt; no cross-wave hazards after.
#define TILE_TAIL2(P)                                                          \
  do {                                                                         \
    RD_A(a, P, 0);                                                             \
    RD_B(b0, P, 0);                                                            \
    RD_B(b1, P, 1);                                                            \
    LG0();                                                                     \
    SP1();                                                                     \
    MMQ(a, b0, 0, 0);                                                          \
    MMQ(a, b1, 0, 2);                                                          \
    SP0();                                                                     \
    RD_A(a, P, 1);                                                             \
    LG0();                                                                     \
    SP1();                                                                     \
    MMQ(a, b1, 4, 2);                                                          \
    MMQ(a, b0, 4, 0);                                                          \
    SP0();                                                                     \
  } while (0)

  for (int it = 0; it < (nk - 2) / 2; ++it) {
    TILE_STEADY(0);
    TILE_STEADY(1);
  }
  TILE_TAIL1(0);
  TILE_TAIL2(1);

  // ---- epilogue. C/D layout: col = lane&15, row = quad*4 + reg ----
  // acc[m][n]: row offset = wm + m*16 (+quad*4+r), col offset = wn + n*16.
#pragma unroll
  for (int n = 0; n < 4; ++n) {
    const int col = tile_n + wn + n * 16 + l15;
    const float bv = bias[col];
#pragma unroll
    for (int m = 0; m < 8; ++m) {
      const int row0 = tile_m + wm + m * 16 + quad * 4;
#pragma unroll
      for (int r = 0; r < 4; ++r) {
        const size_t idx = (size_t)(row0 + r) * N + col;
        float v = acc[m][n][r] + bv;
        if (mode == 0) {
          v = v > 0.f ? v : 0.f;
          Cb[idx] = f2bf(v);
        } else if (mode == 1) {
          accbuf[idx] = v;
          ytbf[idx] = f2bf(y[idx] + 0.5f * v);
        } else if (mode == 2) {
          float a2 = accbuf[idx];
          accbuf[idx] = a2 + 4.f * v;
          ytbf[idx] = f2bf(y[idx] - a2 + 2.f * v);
        } else {
          yout[idx] = y[idx] + (1.f / 6.f) * (accbuf[idx] + v);
        }
      }
    }
  }
  (void)M;
}

// W[K][N] fp32 -> Wt[N][K] bf16 (B^T layout)
__global__ __launch_bounds__(256) void transpose_bf16(
    const float* __restrict__ W, short* __restrict__ Wt, int K, int N) {
  __shared__ float t[32][33];
  int tx = threadIdx.x & 31, ty = threadIdx.x >> 5;
  int k0 = blockIdx.y * 32, n0 = blockIdx.x * 32;
#pragma unroll
  for (int r = 0; r < 32; r += 8)
    t[ty + r][tx] = W[(size_t)(k0 + ty + r) * N + (n0 + tx)];
  __syncthreads();
#pragma unroll
  for (int r = 0; r < 32; r += 8)
    Wt[(size_t)(n0 + ty + r) * K + (k0 + tx)] = f2bf(t[tx][ty + r]);
}

__global__ __launch_bounds__(256) void init_y_kernel(
    const float* __restrict__ x, float* __restrict__ y,
    short* __restrict__ ybf, int n4) {
  int i = blockIdx.x * 256 + threadIdx.x;
  if (i >= n4) return;
  float4 v = ((const float4*)x)[i];
  ((float4*)y)[i] = v;
  short4 b;
  b.x = f2bf(v.x);
  b.y = f2bf(v.y);
  b.z = f2bf(v.z);
  b.w = f2bf(v.w);
  ((short4*)ybf)[i] = b;
}

extern "C" void kernel_launch(void* const* d_in, const int* in_sizes, int n_in,
                              void* d_out, int out_size, void* d_ws,
                              size_t ws_size, hipStream_t stream) {
  const float* x = (const float*)d_in[0];
  const float* W1 = (const float*)d_in[1];
  const float* b1 = (const float*)d_in[2];
  const float* W2 = (const float*)d_in[3];
  const float* b2 = (const float*)d_in[4];
  const float* W3 = (const float*)d_in[5];
  const float* b3 = (const float*)d_in[6];

  const int B = 8192, D = 1024, H = 2048;
  char* ws = (char*)d_ws;
  short* W1t = (short*)(ws + (0ull << 20));   // [H,D] bf16   4 MB
  short* W2t = (short*)(ws + (4ull << 20));   // [H,H] bf16   8 MB
  short* W3t = (short*)(ws + (12ull << 20));  // [D,H] bf16   4 MB
  short* ybf = (short*)(ws + (16ull << 20));  // [B,D] bf16  16 MB
  short* h1 = (short*)(ws + (32ull << 20));   // [B,H] bf16  32 MB
  short* h2 = (short*)(ws + (64ull << 20));   // [B,H] bf16  32 MB
  float* acc = (float*)(ws + (96ull << 20));  // [B,D] f32   32 MB
  float* y = (float*)(ws + (128ull << 20));   // [B,D] f32   32 MB
  float* out = (float*)d_out;

  transpose_bf16<<<dim3(H / 32, D / 32), 256, 0, stream>>>(W1, W1t, D, H);
  transpose_bf16<<<dim3(H / 32, H / 32), 256, 0, stream>>>(W2, W2t, H, H);
  transpose_bf16<<<dim3(D / 32, H / 32), 256, 0, stream>>>(W3, W3t, H, D);
  init_y_kernel<<<(B * D / 4 + 255) / 256, 256, 0, stream>>>(x, y, ybf,
                                                             B * D / 4);

  // Kutta RK3, single step h=1: stages mode 1, 2, 3.
  for (int stg = 1; stg <= 3; ++stg) {
    // layer 1: h1 = relu(ybf @ W1 + b1)   [8192,2048] K=1024, 256 blocks
    gemm8p<<<dim3(H / BN, B / BM), 512, 0, stream>>>(
        ybf, W1t, b1, h1, nullptr, nullptr, nullptr, nullptr, B, H, D, 0);
    // layer 2: h2 = relu(h1 @ W2 + b2)    [8192,2048] K=2048, 256 blocks
    gemm8p<<<dim3(H / BN, B / BM), 512, 0, stream>>>(
        h1, W2t, b2, h2, nullptr, nullptr, nullptr, nullptr, B, H, H, 0);
    // layer 3 + RK3 stage epilogue        [8192,1024] K=2048, 128 blocks
    gemm8p<<<dim3(D / BN, B / BM), 512, 0, stream>>>(
        h2, W3t, b3, nullptr, acc, y, (stg == 3) ? out : nullptr, ybf, B, D,
        H, stg);
  }
}

// Round 3
// 595.895 us; speedup vs baseline: 2.0960x; 1.5207x over previous
//
#include <hip/hip_runtime.h>
#include <hip/hip_bf16.h>
#include <stdint.h>

// Neural-ODE via Kutta RK3 (h=1), bf16 MFMA GEMMs. State y fp32, operands
// bf16, accum fp32. RK3 numerics identical to R6 (absmax 0.05078, passing).
// R9: R7/R8's 8-phase port sat at MfmaUtil 8-11% (tile ~9000cy vs ~800
// predicted). Diagnosis: C++ ds_reads alias the global_load_lds-written LDS
// arrays -> backend conservatively inserts s_waitcnt vmcnt(0) before the
// reads EVERY PHASE, draining the just-issued t+2 staging loads (300-900cy
// x4/tile). The counted vmcnt(6) was never the operative wait. Fix (the
// m201/rule-18 pattern): fragment reads via inline-asm ds_read_b128
// (invisible to alias tracking) + manual lgkmcnt(0) + sched_barrier(0).
// Also: tile 128x256 (8 waves x 64x64 out, acc=64 AGPR, ~150 regs -> no
// spill; R8 spilled ~56 dwords/thread), LDS 96KB, 6 staging loads/tile,
// one vmcnt(6)/tile, K+MODE templated (folds address math).

#define BM 128
#define BN 256
#define BK 64

typedef __attribute__((ext_vector_type(4))) float floatx4;
typedef __attribute__((ext_vector_type(8))) short short8x;

__device__ __forceinline__ short f2bf(float f) {
  unsigned u = __builtin_bit_cast(unsigned, f);
  unsigned r = (u + 0x7fffu + ((u >> 16) & 1u)) >> 16;  // RNE
  return (short)r;
}

#define GLD16(gp, lp)                                                          \
  __builtin_amdgcn_global_load_lds(                                            \
      (const __attribute__((address_space(1))) void*)(gp),                     \
      (__attribute__((address_space(3))) void*)(lp), 16, 0, 0)

#define BAR() __builtin_amdgcn_s_barrier()
#define SP1() __builtin_amdgcn_s_setprio(1)
#define SP0() __builtin_amdgcn_s_setprio(0)
// rule 18: asm ds_read + lgkmcnt(0) must be followed by sched_barrier(0)
#define LG0()                                                                  \
  do {                                                                         \
    asm volatile("s_waitcnt lgkmcnt(0)");                                      \
    __builtin_amdgcn_sched_barrier(0);                                         \
  } while (0)
#define VMC(n) asm volatile("s_waitcnt vmcnt(" #n ")")
#define VMCM(n) asm volatile("s_waitcnt vmcnt(" #n ")" ::: "memory")

// asm ds_read_b128: compiler cannot see LDS aliasing -> no auto vmcnt(0)
#define DSR(d, b, off)                                                         \
  asm volatile("ds_read_b128 %0, %1 offset:%c2"                                \
               : "=v"(d)                                                       \
               : "v"(b), "i"(off))

// C[M,N] = A[M,K](bf16) * Bt[N,K]^T(bf16) + bias, per-mode epilogue (RK3):
//  mode 0: Cb = bf16(relu(v))
//  mode 1: acc = v;           ytbf = bf16(y + 0.5*v)     (k1)
//  mode 2: a=acc; acc=a+4v;   ytbf = bf16(y - a + 2*v)   (k2)
//  mode 3: yout = y + (acc+v)/6                          (k3/update)
template <int K, int MODE>
__global__ __launch_bounds__(512, 2) void gemm8p(
    const short* __restrict__ A, const short* __restrict__ Bt,
    const float* __restrict__ bias, short* __restrict__ Cb,
    float* __restrict__ accbuf, const float* __restrict__ y,
    float* __restrict__ yout, short* __restrict__ ytbf, int N) {
  // LDS: A 2x16KB, B 2x32KB = 96KB. Parity strides: A 8192 shorts (16384B),
  // B 16384 shorts (32768B).
  __shared__ __align__(16) short As[2][BM * BK];
  __shared__ __align__(16) short Bs[2][BN * BK];

  const int tid = threadIdx.x;
  const int lane = tid & 63;
  const int quad = lane >> 4;
  const int l15 = lane & 15;
  const int l7 = lane & 7;
  const int wid = tid >> 6;
  const int wm = (wid >> 2) * 64;  // 2 M-halves
  const int wn = (wid & 3) * 64;   // 4 N-cols; per-wave output 64x64

  // XCD-aware chunked block swizzle (nwg = 512 or 256, both %8==0)
  const int gx = gridDim.x;
  const int nwg = gx * gridDim.y;
  const int bid = blockIdx.y * gx + blockIdx.x;
  const int sb = (bid & 7) * (nwg >> 3) + (bid >> 3);
  const int tile_m = (sb / gx) * BM;
  const int tile_n = (sb % gx) * BN;

  // ---- staging: XOR-swizzled global source, linear LDS dest ----
  // LDS granule slot g of row r holds global granule g ^ (r&7).
  const int t8 = tid >> 3;                       // [0,64)
  const int gsg = (tid & 7) ^ (t8 & 7);
  const int qpart = (t8 >> 5) * 64 + (t8 & 31);  // B row group
  const short* Ag = A + (size_t)(tile_m + t8) * K + gsg * 8;
  const short* Bg = Bt + (size_t)(tile_n + qpart) * K + gsg * 8;
  short* Al0 = &As[0][tid * 8];
  short* Bl0 = &Bs[0][qpart * 64 + (tid & 7) * 8];

  // A rows t8, t8+64 (2 loads); B rows qpart+h*32, +128 (2 loads per half)
#define STG_A(P, ko)                                                           \
  do {                                                                         \
    GLD16(Ag + (ko), Al0 + (P) * 8192);                                        \
    GLD16(Ag + (size_t)64 * K + (ko), Al0 + (P) * 8192 + 4096);                \
  } while (0)
#define STG_B(P, h, ko)                                                        \
  do {                                                                         \
    GLD16(Bg + (size_t)((h) * 32) * K + (ko),                                  \
          Bl0 + (P) * 16384 + (h) * 2048);                                     \
    GLD16(Bg + (size_t)((h) * 32 + 128) * K + (ko),                            \
          Bl0 + (P) * 16384 + (h) * 2048 + 8192);                              \
  } while (0)

  // ---- fragment read base addresses (byte, undo XOR swizzle) ----
  const uint32_t asb = (uint32_t)(uintptr_t)&As[0][0];
  const uint32_t bsb = (uint32_t)(uintptr_t)&Bs[0][0];
  const uint32_t aab0 = asb + 2u * ((wm + l15) * 64 + (quad ^ l7) * 8);
  const uint32_t aab1 = asb + 2u * ((wm + l15) * 64 + (((4 + quad) ^ l7)) * 8);
  const uint32_t bab0 = bsb + 2u * ((wn + l15) * 64 + (quad ^ l7) * 8);
  const uint32_t bab1 = bsb + 2u * ((wn + l15) * 64 + (((4 + quad) ^ l7)) * 8);

  // dst[i][kk]; i = 16-row step within the 32-row half, kk = K-half.
#define RD_A(dst, P, mih)                                                      \
  do {                                                                         \
    DSR(dst[0][0], aab0, (P) * 16384 + (mih) * 4096);                          \
    DSR(dst[0][1], aab1, (P) * 16384 + (mih) * 4096);                          \
    DSR(dst[1][0], aab0, (P) * 16384 + (mih) * 4096 + 2048);                   \
    DSR(dst[1][1], aab1, (P) * 16384 + (mih) * 4096 + 2048);                   \
  } while (0)
#define RD_B(dst, P, njh)                                                      \
  do {                                                                         \
    DSR(dst[0][0], bab0, (P) * 32768 + (njh) * 4096);                          \
    DSR(dst[0][1], bab1, (P) * 32768 + (njh) * 4096);                          \
    DSR(dst[1][0], bab0, (P) * 32768 + (njh) * 4096 + 2048);                   \
    DSR(dst[1][1], bab1, (P) * 32768 + (njh) * 4096 + 2048);                   \
  } while (0)

  floatx4 acc[4][4];
#pragma unroll
  for (int i = 0; i < 4; ++i)
#pragma unroll
    for (int j = 0; j < 4; ++j) acc[i][j] = (floatx4){0.f, 0.f, 0.f, 0.f};

  short8x a[2][2], b0[2][2], b1[2][2];

#define MMQ(af, bf, mi0, nj0)                                                  \
  do {                                                                         \
    _Pragma("unroll") for (int i = 0; i < 2; ++i) {                            \
      _Pragma("unroll") for (int j = 0; j < 2; ++j) {                          \
        acc[(mi0) + i][(nj0) + j] = __builtin_amdgcn_mfma_f32_16x16x32_bf16(   \
            af[i][0], bf[j][0], acc[(mi0) + i][(nj0) + j], 0, 0, 0);           \
        acc[(mi0) + i][(nj0) + j] = __builtin_amdgcn_mfma_f32_16x16x32_bf16(   \
            af[i][1], bf[j][1], acc[(mi0) + i][(nj0) + j], 0, 0, 0);           \
      }                                                                        \
    }                                                                          \
  } while (0)

  constexpr int NK = K / BK;
  int ko;

  // ---- prologue: stage K-tiles 0 (P0) and 1 (P1), 6 loads each ----
  STG_B(0, 0, 0);
  STG_B(0, 1, 0);
  STG_A(0, 0);
  STG_B(1, 0, 64);
  STG_B(1, 1, 64);
  STG_A(1, 64);
  VMC(6);  // tile 0 landed; tile 1's 6 loads in flight
  BAR();
  ko = 128;  // k-offset (shorts) of next tile to stage (= tile 2)

  // Z-order: p0 a_lo*b0, p1 a_lo*b1, p2 a_hi*b1, p3 a_hi*b0.
  // Staging t+2 into same parity: B0 at p1 (b0 reads confirmed p0),
  // B1 at p2 (b1 reads p1), A at p3 (a_hi reads p2). vmcnt(6) once per
  // tile at p3 (before trailing barrier): drains t+1, leaves t+2's 6.
#define TILE_STEADY(P)                                                         \
  do {                                                                         \
    RD_A(a, P, 0);                                                             \
    RD_B(b0, P, 0);                                                            \
    BAR();                                                                     \
    LG0();                                                                     \
    SP1();                                                                     \
    MMQ(a, b0, 0, 0);                                                          \
    SP0();                                                                     \
    BAR();                                                                     \
    RD_B(b1, P, 1);                                                            \
    STG_B(P, 0, ko);                                                           \
    BAR();                                                                     \
    LG0();                                                                     \
    SP1();                                                                     \
    MMQ(a, b1, 0, 2);                                                          \
    SP0();                                                                     \
    BAR();                                                                     \
    RD_A(a, P, 1);                                                             \
    STG_B(P, 1, ko);                                                           \
    BAR();                                                                     \
    LG0();                                                                     \
    SP1();                                                                     \
    MMQ(a, b1, 2, 2);                                                          \
    SP0();                                                                     \
    BAR();                                                                     \
    STG_A(P, ko);                                                              \
    BAR();                                                                     \
    SP1();                                                                     \
    MMQ(a, b0, 2, 0);                                                          \
    SP0();                                                                     \
    VMC(6);                                                                    \
    BAR();                                                                     \
    ko += 64;                                                                  \
  } while (0)

  // tile NK-2 (parity 0): no staging; vmcnt(0) drains the last tile.
#define TILE_TAIL1()                                                           \
  do {                                                                         \
    RD_A(a, 0, 0);                                                             \
    RD_B(b0, 0, 0);                                                            \
    BAR();                                                                     \
    LG0();                                                                     \
    SP1();                                                                     \
    MMQ(a, b0, 0, 0);                                                          \
    SP0();                                                                     \
    BAR();                                                                     \
    RD_B(b1, 0, 1);                                                            \
    BAR();                                                                     \
    LG0();                                                                     \
    SP1();                                                                     \
    MMQ(a, b1, 0, 2);                                                          \
    SP0();                                                                     \
    BAR();                                                                     \
    RD_A(a, 0, 1);                                                             \
    BAR();                                                                     \
    LG0();                                                                     \
    SP1();                                                                     \
    MMQ(a, b1, 2, 2);                                                          \
    SP0();                                                                     \
    BAR();                                                                     \
    SP1();                                                                     \
    MMQ(a, b0, 2, 0);                                                          \
    SP0();                                                                     \
    VMCM(0);                                                                   \
    BAR();                                                                     \
  } while (0)

  // tile NK-1 (parity 1): last tile; register deps only.
#define TILE_TAIL2()                                                           \
  do {                                                                         \
    RD_A(a, 1, 0);                                                             \
    RD_B(b0, 1, 0);                                                            \
    RD_B(b1, 1, 1);                                                            \
    LG0();                                                                     \
    SP1();                                                                     \
    MMQ(a, b0, 0, 0);                                                          \
    MMQ(a, b1, 0, 2);                                                          \
    SP0();                                                                     \
    RD_A(a, 1, 1);                                                             \
    LG0();                                                                     \
    SP1();                                                                     \
    MMQ(a, b1, 2, 2);                                                          \
    MMQ(a, b0, 2, 0);                                                          \
    SP0();                                                                     \
  } while (0)

  for (int it = 0; it < (NK - 2) / 2; ++it) {
    TILE_STEADY(0);
    TILE_STEADY(1);
  }
  TILE_TAIL1();
  TILE_TAIL2();

  // ---- epilogue. C/D layout: col = lane&15, row = quad*4 + reg ----
#pragma unroll
  for (int n = 0; n < 4; ++n) {
    const int col = tile_n + wn + n * 16 + l15;
    const float bv = bias[col];
#pragma unroll
    for (int m = 0; m < 4; ++m) {
      const int row0 = tile_m + wm + m * 16 + quad * 4;
#pragma unroll
      for (int r = 0; r < 4; ++r) {
        const size_t idx = (size_t)(row0 + r) * N + col;
        float v = acc[m][n][r] + bv;
        if (MODE == 0) {
          v = v > 0.f ? v : 0.f;
          Cb[idx] = f2bf(v);
        } else if (MODE == 1) {
          accbuf[idx] = v;
          ytbf[idx] = f2bf(y[idx] + 0.5f * v);
        } else if (MODE == 2) {
          float a2 = accbuf[idx];
          accbuf[idx] = a2 + 4.f * v;
          ytbf[idx] = f2bf(y[idx] - a2 + 2.f * v);
        } else {
          yout[idx] = y[idx] + (1.f / 6.f) * (accbuf[idx] + v);
        }
      }
    }
  }
}

// W[K][N] fp32 -> Wt[N][K] bf16 (B^T layout)
__global__ __launch_bounds__(256) void transpose_bf16(
    const float* __restrict__ W, short* __restrict__ Wt, int K, int N) {
  __shared__ float t[32][33];
  int tx = threadIdx.x & 31, ty = threadIdx.x >> 5;
  int k0 = blockIdx.y * 32, n0 = blockIdx.x * 32;
#pragma unroll
  for (int r = 0; r < 32; r += 8)
    t[ty + r][tx] = W[(size_t)(k0 + ty + r) * N + (n0 + tx)];
  __syncthreads();
#pragma unroll
  for (int r = 0; r < 32; r += 8)
    Wt[(size_t)(n0 + ty + r) * K + (k0 + tx)] = f2bf(t[tx][ty + r]);
}

__global__ __launch_bounds__(256) void init_y_kernel(
    const float* __restrict__ x, float* __restrict__ y,
    short* __restrict__ ybf, int n4) {
  int i = blockIdx.x * 256 + threadIdx.x;
  if (i >= n4) return;
  float4 v = ((const float4*)x)[i];
  ((float4*)y)[i] = v;
  short4 b;
  b.x = f2bf(v.x);
  b.y = f2bf(v.y);
  b.z = f2bf(v.z);
  b.w = f2bf(v.w);
  ((short4*)ybf)[i] = b;
}

extern "C" void kernel_launch(void* const* d_in, const int* in_sizes, int n_in,
                              void* d_out, int out_size, void* d_ws,
                              size_t ws_size, hipStream_t stream) {
  const float* x = (const float*)d_in[0];
  const float* W1 = (const float*)d_in[1];
  const float* b1 = (const float*)d_in[2];
  const float* W2 = (const float*)d_in[3];
  const float* b2 = (const float*)d_in[4];
  const float* W3 = (const float*)d_in[5];
  const float* b3 = (const float*)d_in[6];

  const int B = 8192, D = 1024, H = 2048;
  char* ws = (char*)d_ws;
  short* W1t = (short*)(ws + (0ull << 20));   // [H,D] bf16   4 MB
  short* W2t = (short*)(ws + (4ull << 20));   // [H,H] bf16   8 MB
  short* W3t = (short*)(ws + (12ull << 20));  // [D,H] bf16   4 MB
  short* ybf = (short*)(ws + (16ull << 20));  // [B,D] bf16  16 MB
  short* h1 = (short*)(ws + (32ull << 20));   // [B,H] bf16  32 MB
  short* h2 = (short*)(ws + (64ull << 20));   // [B,H] bf16  32 MB
  float* acc = (float*)(ws + (96ull << 20));  // [B,D] f32   32 MB
  float* y = (float*)(ws + (128ull << 20));   // [B,D] f32   32 MB
  float* out = (float*)d_out;

  transpose_bf16<<<dim3(H / 32, D / 32), 256, 0, stream>>>(W1, W1t, D, H);
  transpose_bf16<<<dim3(H / 32, H / 32), 256, 0, stream>>>(W2, W2t, H, H);
  transpose_bf16<<<dim3(D / 32, H / 32), 256, 0, stream>>>(W3, W3t, H, D);
  init_y_kernel<<<(B * D / 4 + 255) / 256, 256, 0, stream>>>(x, y, ybf,
                                                             B * D / 4);

  const dim3 g12(H / BN, B / BM);  // (8, 64) = 512 blocks
  const dim3 g3(D / BN, B / BM);   // (4, 64) = 256 blocks

  // Kutta RK3, single step h=1: stages mode 1, 2, 3.
  for (int stg = 1; stg <= 3; ++stg) {
    gemm8p<1024, 0><<<g12, 512, 0, stream>>>(ybf, W1t, b1, h1, nullptr,
                                             nullptr, nullptr, nullptr, H);
    gemm8p<2048, 0><<<g12, 512, 0, stream>>>(h1, W2t, b2, h2, nullptr, nullptr,
                                             nullptr, nullptr, H);
    if (stg == 1)
      gemm8p<2048, 1><<<g3, 512, 0, stream>>>(h2, W3t, b3, nullptr, acc, y,
                                              nullptr, ybf, D);
    else if (stg == 2)
      gemm8p<2048, 2><<<g3, 512, 0, stream>>>(h2, W3t, b3, nullptr, acc, y,
                                              nullptr, ybf, D);
    else
      gemm8p<2048, 3><<<g3, 512, 0, stream>>>(h2, W3t, b3, nullptr, acc, y,
                                              out, ybf, D);
  }
}

// Round 4
// 563.220 us; speedup vs baseline: 2.2175x; 1.0580x over previous
//
#include <hip/hip_runtime.h>
#include <hip/hip_bf16.h>
#include <stdint.h>

// Neural-ODE via Kutta RK3 (h=1), bf16 MFMA GEMMs. State y fp32, operands
// bf16, accum fp32. RK3 numerics identical to R6 (absmax 0.05078, passing).
// R10: R9 (596us) fixed the per-phase vmcnt drain via asm ds_read (MfmaUtil
// 40%). Remaining gap to m201 (62%): tile size. New gemm256 for layers 1-2:
// 256x256 tile, 8 waves x 128x64 out, acc[8][4], 64 MFMA/tile/wave (2x the
// matrix work per phase against the same per-phase fixed overhead), LDS
// 128KB, 8 staging loads/tile, counted vmcnt(8). Grid 256 = exactly 1
// block/CU, single round. Layer 3 (N=1024) keeps the R9 128x256 kernel:
// 256^2 there would leave half the CUs idle (128 blocks).

#define BM 128
#define BN 256
#define BK 64

typedef __attribute__((ext_vector_type(4))) float floatx4;
typedef __attribute__((ext_vector_type(8))) short short8x;

__device__ __forceinline__ short f2bf(float f) {
  unsigned u = __builtin_bit_cast(unsigned, f);
  unsigned r = (u + 0x7fffu + ((u >> 16) & 1u)) >> 16;  // RNE
  return (short)r;
}

#define GLD16(gp, lp)                                                          \
  __builtin_amdgcn_global_load_lds(                                            \
      (const __attribute__((address_space(1))) void*)(gp),                     \
      (__attribute__((address_space(3))) void*)(lp), 16, 0, 0)

#define BAR() __builtin_amdgcn_s_barrier()
#define SP1() __builtin_amdgcn_s_setprio(1)
#define SP0() __builtin_amdgcn_s_setprio(0)
// rule 18: asm ds_read + lgkmcnt(0) must be followed by sched_barrier(0)
#define LG0()                                                                  \
  do {                                                                         \
    asm volatile("s_waitcnt lgkmcnt(0)");                                      \
    __builtin_amdgcn_sched_barrier(0);                                         \
  } while (0)
#define VMC(n) asm volatile("s_waitcnt vmcnt(" #n ")")
#define VMCM(n) asm volatile("s_waitcnt vmcnt(" #n ")" ::: "memory")

// asm ds_read_b128: compiler cannot see LDS aliasing -> no auto vmcnt(0)
#define DSR(d, b, off)                                                         \
  asm volatile("ds_read_b128 %0, %1 offset:%c2"                                \
               : "=v"(d)                                                       \
               : "v"(b), "i"(off))

// ============================================================================
// gemm256: 256x256 tile, relu+bf16 epilogue only (layers 1 and 2).
// ============================================================================
template <int K>
__global__ __launch_bounds__(512, 2) void gemm256(
    const short* __restrict__ A, const short* __restrict__ Bt,
    const float* __restrict__ bias, short* __restrict__ Cb, int N) {
  // LDS: A 2x32KB, B 2x32KB = 128KB. Parity strides 16384 shorts (32KB).
  __shared__ __align__(16) short As[2][256 * 64];
  __shared__ __align__(16) short Bs[2][256 * 64];

  const int tid = threadIdx.x;
  const int lane = tid & 63;
  const int quad = lane >> 4;
  const int l15 = lane & 15;
  const int l7 = lane & 7;
  const int wid = tid >> 6;
  const int wm = (wid >> 2) * 128;  // 2 M wave-halves of 128 rows
  const int wn = (wid & 3) * 64;    // 4 N wave-cols; per-wave out 128x64

  // XCD-aware chunked block swizzle (nwg = 256, %8==0)
  const int gx = gridDim.x;
  const int nwg = gx * gridDim.y;
  const int bid = blockIdx.y * gx + blockIdx.x;
  const int sb = (bid & 7) * (nwg >> 3) + (bid >> 3);
  const int tile_m = (sb / gx) * 256;
  const int tile_n = (sb % gx) * 256;

  // ---- staging: XOR-swizzled global source, linear LDS dest ----
  const int t8 = tid >> 3;  // [0,64)
  const int gsg = (tid & 7) ^ (t8 & 7);
  const int qpart = (t8 >> 5) * 64 + (t8 & 31);  // B row group
  const short* Ag = A + (size_t)(tile_m + t8) * K + gsg * 8;
  const short* Bg = Bt + (size_t)(tile_n + qpart) * K + gsg * 8;
  short* Al0 = &As[0][tid * 8];
  short* Bl0 = &Bs[0][qpart * 64 + (tid & 7) * 8];

  // A half h (frag rows h*4..h*4+3 of both wave-groups) = global rows
  // {h*64..h*64+63} u {128+h*64..}: 2 issues of 64 rows.
#define STG_A6(P, h, ko)                                                       \
  do {                                                                         \
    GLD16(Ag + (size_t)((h) * 64) * K + (ko),                                  \
          Al0 + (P) * 16384 + (h) * 4096);                                     \
    GLD16(Ag + (size_t)(128 + (h) * 64) * K + (ko),                            \
          Al0 + (P) * 16384 + 8192 + (h) * 4096);                              \
  } while (0)
  // B half h = rows {q*64 + h*32 .. +31}, q=0..3: 2 issues.
#define STG_B6(P, h, ko)                                                       \
  do {                                                                         \
    GLD16(Bg + (size_t)((h) * 32) * K + (ko),                                  \
          Bl0 + (P) * 16384 + (h) * 2048);                                     \
    GLD16(Bg + (size_t)((h) * 32 + 128) * K + (ko),                            \
          Bl0 + (P) * 16384 + (h) * 2048 + 8192);                              \
  } while (0)

  // ---- fragment read bases (byte, undo XOR swizzle) ----
  const uint32_t asb = (uint32_t)(uintptr_t)&As[0][0];
  const uint32_t bsb = (uint32_t)(uintptr_t)&Bs[0][0];
  const uint32_t aab0 = asb + 2u * ((wm + l15) * 64 + (quad ^ l7) * 8);
  const uint32_t aab1 = asb + 2u * ((wm + l15) * 64 + (((4 + quad) ^ l7)) * 8);
  const uint32_t bab0 = bsb + 2u * ((wn + l15) * 64 + (quad ^ l7) * 8);
  const uint32_t bab1 = bsb + 2u * ((wn + l15) * 64 + (((4 + quad) ^ l7)) * 8);

  // A frag rows (within half mih): offs mih*8192 + i*2048, i=0..3.
#define RD_A6(dst, P, mih)                                                     \
  do {                                                                         \
    DSR(dst[0][0], aab0, (P) * 32768 + (mih) * 8192);                          \
    DSR(dst[0][1], aab1, (P) * 32768 + (mih) * 8192);                          \
    DSR(dst[1][0], aab0, (P) * 32768 + (mih) * 8192 + 2048);                   \
    DSR(dst[1][1], aab1, (P) * 32768 + (mih) * 8192 + 2048);                   \
    DSR(dst[2][0], aab0, (P) * 32768 + (mih) * 8192 + 4096);                   \
    DSR(dst[2][1], aab1, (P) * 32768 + (mih) * 8192 + 4096);                   \
    DSR(dst[3][0], aab0, (P) * 32768 + (mih) * 8192 + 6144);                   \
    DSR(dst[3][1], aab1, (P) * 32768 + (mih) * 8192 + 6144);                   \
  } while (0)
#define RD_B6(dst, P, njh)                                                     \
  do {                                                                         \
    DSR(dst[0][0], bab0, (P) * 32768 + (njh) * 4096);                          \
    DSR(dst[0][1], bab1, (P) * 32768 + (njh) * 4096);                          \
    DSR(dst[1][0], bab0, (P) * 32768 + (njh) * 4096 + 2048);                   \
    DSR(dst[1][1], bab1, (P) * 32768 + (njh) * 4096 + 2048);                   \
  } while (0)

  floatx4 acc[8][4];
#pragma unroll
  for (int i = 0; i < 8; ++i)
#pragma unroll
    for (int j = 0; j < 4; ++j) acc[i][j] = (floatx4){0.f, 0.f, 0.f, 0.f};

  short8x a[4][2], b0[2][2], b1[2][2];

#define MMQ6(af, bf, mi0, nj0)                                                 \
  do {                                                                         \
    _Pragma("unroll") for (int i = 0; i < 4; ++i) {                            \
      _Pragma("unroll") for (int j = 0; j < 2; ++j) {                          \
        acc[(mi0) + i][(nj0) + j] = __builtin_amdgcn_mfma_f32_16x16x32_bf16(   \
            af[i][0], bf[j][0], acc[(mi0) + i][(nj0) + j], 0, 0, 0);           \
        acc[(mi0) + i][(nj0) + j] = __builtin_amdgcn_mfma_f32_16x16x32_bf16(   \
            af[i][1], bf[j][1], acc[(mi0) + i][(nj0) + j], 0, 0, 0);           \
      }                                                                        \
    }                                                                          \
  } while (0)

  constexpr int NK = K / BK;
  int ko;

  // prologue: stage K-tiles 0 (P0) and 1 (P1), 8 loads each
  STG_A6(0, 0, 0);
  STG_B6(0, 0, 0);
  STG_B6(0, 1, 0);
  STG_A6(0, 1, 0);
  STG_A6(1, 0, 64);
  STG_B6(1, 0, 64);
  STG_B6(1, 1, 64);
  STG_A6(1, 1, 64);
  VMC(8);  // tile 0 landed; tile 1's 8 loads remain in flight
  BAR();
  ko = 128;

  // Z-order: p0 a_lo*b0, p1 a_lo*b1, p2 a_hi*b1, p3 a_hi*b0. Staging t+2
  // into same parity right after each region's last confirmed read; one
  // vmcnt(8) per tile (drains t+1, leaves t+2's 8 in flight).
#define T256_STEADY(P)                                                         \
  do {                                                                         \
    RD_A6(a, P, 0);                                                            \
    RD_B6(b0, P, 0);                                                           \
    BAR();                                                                     \
    LG0();                                                                     \
    SP1();                                                                     \
    MMQ6(a, b0, 0, 0);                                                         \
    SP0();                                                                     \
    BAR();                                                                     \
    RD_B6(b1, P, 1);                                                           \
    STG_A6(P, 0, ko);                                                          \
    STG_B6(P, 0, ko);                                                          \
    BAR();                                                                     \
    LG0();                                                                     \
    SP1();                                                                     \
    MMQ6(a, b1, 0, 2);                                                         \
    SP0();                                                                     \
    BAR();                                                                     \
    RD_A6(a, P, 1);                                                            \
    STG_B6(P, 1, ko);                                                          \
    BAR();                                                                     \
    LG0();                                                                     \
    SP1();                                                                     \
    MMQ6(a, b1, 4, 2);                                                         \
    SP0();                                                                     \
    BAR();                                                                     \
    STG_A6(P, 1, ko);                                                          \
    BAR();                                                                     \
    SP1();                                                                     \
    MMQ6(a, b0, 4, 0);                                                         \
    SP0();                                                                     \
    VMC(8);                                                                    \
    BAR();                                                                     \
    ko += 64;                                                                  \
  } while (0)

#define T256_TAIL1()                                                           \
  do {                                                                         \
    RD_A6(a, 0, 0);                                                            \
    RD_B6(b0, 0, 0);                                                           \
    BAR();                                                                     \
    LG0();                                                                     \
    SP1();                                                                     \
    MMQ6(a, b0, 0, 0);                                                         \
    SP0();                                                                     \
    BAR();                                                                     \
    RD_B6(b1, 0, 1);                                                           \
    BAR();                                                                     \
    LG0();                                                                     \
    SP1();                                                                     \
    MMQ6(a, b1, 0, 2);                                                         \
    SP0();                                                                     \
    BAR();                                                                     \
    RD_A6(a, 0, 1);                                                            \
    BAR();                                                                     \
    LG0();                                                                     \
    SP1();                                                                     \
    MMQ6(a, b1, 4, 2);                                                         \
    SP0();                                                                     \
    BAR();                                                                     \
    SP1();                                                                     \
    MMQ6(a, b0, 4, 0);                                                         \
    SP0();                                                                     \
    VMCM(0);                                                                   \
    BAR();                                                                     \
  } while (0)

#define T256_TAIL2()                                                           \
  do {                                                                         \
    RD_A6(a, 1, 0);                                                            \
    RD_B6(b0, 1, 0);                                                           \
    RD_B6(b1, 1, 1);                                                           \
    LG0();                                                                     \
    SP1();                                                                     \
    MMQ6(a, b0, 0, 0);                                                         \
    MMQ6(a, b1, 0, 2);                                                         \
    SP0();                                                                     \
    RD_A6(a, 1, 1);                                                            \
    LG0();                                                                     \
    SP1();                                                                     \
    MMQ6(a, b1, 4, 2);                                                         \
    MMQ6(a, b0, 4, 0);                                                         \
    SP0();                                                                     \
  } while (0)

  for (int it = 0; it < (NK - 2) / 2; ++it) {
    T256_STEADY(0);
    T256_STEADY(1);
  }
  T256_TAIL1();
  T256_TAIL2();

  // epilogue (mode-0 only): Cb = bf16(relu(v + bias))
#pragma unroll
  for (int n = 0; n < 4; ++n) {
    const int col = tile_n + wn + n * 16 + l15;
    const float bv = bias[col];
#pragma unroll
    for (int m = 0; m < 8; ++m) {
      const int row0 = tile_m + wm + m * 16 + quad * 4;
#pragma unroll
      for (int r = 0; r < 4; ++r) {
        const size_t idx = (size_t)(row0 + r) * N + col;
        float v = acc[m][n][r] + bv;
        v = v > 0.f ? v : 0.f;
        Cb[idx] = f2bf(v);
      }
    }
  }
}

// ============================================================================
// gemm8p: 128x256 tile (R9, proven). Used for layer 3 (N=1024: grid stays
// 256 blocks = 1/CU; a 256^2 tile there would idle half the CUs).
// ============================================================================
template <int K, int MODE>
__global__ __launch_bounds__(512, 2) void gemm8p(
    const short* __restrict__ A, const short* __restrict__ Bt,
    const float* __restrict__ bias, short* __restrict__ Cb,
    float* __restrict__ accbuf, const float* __restrict__ y,
    float* __restrict__ yout, short* __restrict__ ytbf, int N) {
  __shared__ __align__(16) short As[2][BM * BK];
  __shared__ __align__(16) short Bs[2][BN * BK];

  const int tid = threadIdx.x;
  const int lane = tid & 63;
  const int quad = lane >> 4;
  const int l15 = lane & 15;
  const int l7 = lane & 7;
  const int wid = tid >> 6;
  const int wm = (wid >> 2) * 64;
  const int wn = (wid & 3) * 64;

  const int gx = gridDim.x;
  const int nwg = gx * gridDim.y;
  const int bid = blockIdx.y * gx + blockIdx.x;
  const int sb = (bid & 7) * (nwg >> 3) + (bid >> 3);
  const int tile_m = (sb / gx) * BM;
  const int tile_n = (sb % gx) * BN;

  const int t8 = tid >> 3;
  const int gsg = (tid & 7) ^ (t8 & 7);
  const int qpart = (t8 >> 5) * 64 + (t8 & 31);
  const short* Ag = A + (size_t)(tile_m + t8) * K + gsg * 8;
  const short* Bg = Bt + (size_t)(tile_n + qpart) * K + gsg * 8;
  short* Al0 = &As[0][tid * 8];
  short* Bl0 = &Bs[0][qpart * 64 + (tid & 7) * 8];

#define STG_A(P, ko)                                                           \
  do {                                                                         \
    GLD16(Ag + (ko), Al0 + (P) * 8192);                                        \
    GLD16(Ag + (size_t)64 * K + (ko), Al0 + (P) * 8192 + 4096);                \
  } while (0)
#define STG_B(P, h, ko)                                                        \
  do {                                                                         \
    GLD16(Bg + (size_t)((h) * 32) * K + (ko),                                  \
          Bl0 + (P) * 16384 + (h) * 2048);                                     \
    GLD16(Bg + (size_t)((h) * 32 + 128) * K + (ko),                            \
          Bl0 + (P) * 16384 + (h) * 2048 + 8192);                              \
  } while (0)

  const uint32_t asb = (uint32_t)(uintptr_t)&As[0][0];
  const uint32_t bsb = (uint32_t)(uintptr_t)&Bs[0][0];
  const uint32_t aab0 = asb + 2u * ((wm + l15) * 64 + (quad ^ l7) * 8);
  const uint32_t aab1 = asb + 2u * ((wm + l15) * 64 + (((4 + quad) ^ l7)) * 8);
  const uint32_t bab0 = bsb + 2u * ((wn + l15) * 64 + (quad ^ l7) * 8);
  const uint32_t bab1 = bsb + 2u * ((wn + l15) * 64 + (((4 + quad) ^ l7)) * 8);

#define RD_A(dst, P, mih)                                                      \
  do {                                                                         \
    DSR(dst[0][0], aab0, (P) * 16384 + (mih) * 4096);                          \
    DSR(dst[0][1], aab1, (P) * 16384 + (mih) * 4096);                          \
    DSR(dst[1][0], aab0, (P) * 16384 + (mih) * 4096 + 2048);                   \
    DSR(dst[1][1], aab1, (P) * 16384 + (mih) * 4096 + 2048);                   \
  } while (0)
#define RD_B(dst, P, njh)                                                      \
  do {                                                                         \
    DSR(dst[0][0], bab0, (P) * 32768 + (njh) * 4096);                          \
    DSR(dst[0][1], bab1, (P) * 32768 + (njh) * 4096);                          \
    DSR(dst[1][0], bab0, (P) * 32768 + (njh) * 4096 + 2048);                   \
    DSR(dst[1][1], bab1, (P) * 32768 + (njh) * 4096 + 2048);                   \
  } while (0)

  floatx4 acc[4][4];
#pragma unroll
  for (int i = 0; i < 4; ++i)
#pragma unroll
    for (int j = 0; j < 4; ++j) acc[i][j] = (floatx4){0.f, 0.f, 0.f, 0.f};

  short8x a[2][2], b0[2][2], b1[2][2];

#define MMQ(af, bf, mi0, nj0)                                                  \
  do {                                                                         \
    _Pragma("unroll") for (int i = 0; i < 2; ++i) {                            \
      _Pragma("unroll") for (int j = 0; j < 2; ++j) {                          \
        acc[(mi0) + i][(nj0) + j] = __builtin_amdgcn_mfma_f32_16x16x32_bf16(   \
            af[i][0], bf[j][0], acc[(mi0) + i][(nj0) + j], 0, 0, 0);           \
        acc[(mi0) + i][(nj0) + j] = __builtin_amdgcn_mfma_f32_16x16x32_bf16(   \
            af[i][1], bf[j][1], acc[(mi0) + i][(nj0) + j], 0, 0, 0);           \
      }                                                                        \
    }                                                                          \
  } while (0)

  constexpr int NK = K / BK;
  int ko;

  STG_B(0, 0, 0);
  STG_B(0, 1, 0);
  STG_A(0, 0);
  STG_B(1, 0, 64);
  STG_B(1, 1, 64);
  STG_A(1, 64);
  VMC(6);
  BAR();
  ko = 128;

#define TILE_STEADY(P)                                                         \
  do {                                                                         \
    RD_A(a, P, 0);                                                             \
    RD_B(b0, P, 0);                                                            \
    BAR();                                                                     \
    LG0();                                                                     \
    SP1();                                                                     \
    MMQ(a, b0, 0, 0);                                                          \
    SP0();                                                                     \
    BAR();                                                                     \
    RD_B(b1, P, 1);                                                            \
    STG_B(P, 0, ko);                                                           \
    BAR();                                                                     \
    LG0();                                                                     \
    SP1();                                                                     \
    MMQ(a, b1, 0, 2);                                                          \
    SP0();                                                                     \
    BAR();                                                                     \
    RD_A(a, P, 1);                                                             \
    STG_B(P, 1, ko);                                                           \
    BAR();                                                                     \
    LG0();                                                                     \
    SP1();                                                                     \
    MMQ(a, b1, 2, 2);                                                          \
    SP0();                                                                     \
    BAR();                                                                     \
    STG_A(P, ko);                                                              \
    BAR();                                                                     \
    SP1();                                                                     \
    MMQ(a, b0, 2, 0);                                                          \
    SP0();                                                                     \
    VMC(6);                                                                    \
    BAR();                                                                     \
    ko += 64;                                                                  \
  } while (0)

#define TILE_TAIL1()                                                           \
  do {                                                                         \
    RD_A(a, 0, 0);                                                             \
    RD_B(b0, 0, 0);                                                            \
    BAR();                                                                     \
    LG0();                                                                     \
    SP1();                                                                     \
    MMQ(a, b0, 0, 0);                                                          \
    SP0();                                                                     \
    BAR();                                                                     \
    RD_B(b1, 0, 1);                                                            \
    BAR();                                                                     \
    LG0();                                                                     \
    SP1();                                                                     \
    MMQ(a, b1, 0, 2);                                                          \
    SP0();                                                                     \
    BAR();                                                                     \
    RD_A(a, 0, 1);                                                             \
    BAR();                                                                     \
    LG0();                                                                     \
    SP1();                                                                     \
    MMQ(a, b1, 2, 2);                                                          \
    SP0();                                                                     \
    BAR();                                                                     \
    SP1();                                                                     \
    MMQ(a, b0, 2, 0);                                                          \
    SP0();                                                                     \
    VMCM(0);                                                                   \
    BAR();                                                                     \
  } while (0)

#define TILE_TAIL2()                                                           \
  do {                                                                         \
    RD_A(a, 1, 0);                                                             \
    RD_B(b0, 1, 0);                                                            \
    RD_B(b1, 1, 1);                                                            \
    LG0();                                                                     \
    SP1();                                                                     \
    MMQ(a, b0, 0, 0);                                                          \
    MMQ(a, b1, 0, 2);                                                          \
    SP0();                                                                     \
    RD_A(a, 1, 1);                                                             \
    LG0();                                                                     \
    SP1();                                                                     \
    MMQ(a, b1, 2, 2);                                                          \
    MMQ(a, b0, 2, 0);                                                          \
    SP0();                                                                     \
  } while (0)

  for (int it = 0; it < (NK - 2) / 2; ++it) {
    TILE_STEADY(0);
    TILE_STEADY(1);
  }
  TILE_TAIL1();
  TILE_TAIL2();

#pragma unroll
  for (int n = 0; n < 4; ++n) {
    const int col = tile_n + wn + n * 16 + l15;
    const float bv = bias[col];
#pragma unroll
    for (int m = 0; m < 4; ++m) {
      const int row0 = tile_m + wm + m * 16 + quad * 4;
#pragma unroll
      for (int r = 0; r < 4; ++r) {
        const size_t idx = (size_t)(row0 + r) * N + col;
        float v = acc[m][n][r] + bv;
        if (MODE == 0) {
          v = v > 0.f ? v : 0.f;
          Cb[idx] = f2bf(v);
        } else if (MODE == 1) {
          accbuf[idx] = v;
          ytbf[idx] = f2bf(y[idx] + 0.5f * v);
        } else if (MODE == 2) {
          float a2 = accbuf[idx];
          accbuf[idx] = a2 + 4.f * v;
          ytbf[idx] = f2bf(y[idx] - a2 + 2.f * v);
        } else {
          yout[idx] = y[idx] + (1.f / 6.f) * (accbuf[idx] + v);
        }
      }
    }
  }
}

// W[K][N] fp32 -> Wt[N][K] bf16 (B^T layout)
__global__ __launch_bounds__(256) void transpose_bf16(
    const float* __restrict__ W, short* __restrict__ Wt, int K, int N) {
  __shared__ float t[32][33];
  int tx = threadIdx.x & 31, ty = threadIdx.x >> 5;
  int k0 = blockIdx.y * 32, n0 = blockIdx.x * 32;
#pragma unroll
  for (int r = 0; r < 32; r += 8)
    t[ty + r][tx] = W[(size_t)(k0 + ty + r) * N + (n0 + tx)];
  __syncthreads();
#pragma unroll
  for (int r = 0; r < 32; r += 8)
    Wt[(size_t)(n0 + ty + r) * K + (k0 + tx)] = f2bf(t[tx][ty + r]);
}

__global__ __launch_bounds__(256) void init_y_kernel(
    const float* __restrict__ x, float* __restrict__ y,
    short* __restrict__ ybf, int n4) {
  int i = blockIdx.x * 256 + threadIdx.x;
  if (i >= n4) return;
  float4 v = ((const float4*)x)[i];
  ((float4*)y)[i] = v;
  short4 b;
  b.x = f2bf(v.x);
  b.y = f2bf(v.y);
  b.z = f2bf(v.z);
  b.w = f2bf(v.w);
  ((short4*)ybf)[i] = b;
}

extern "C" void kernel_launch(void* const* d_in, const int* in_sizes, int n_in,
                              void* d_out, int out_size, void* d_ws,
                              size_t ws_size, hipStream_t stream) {
  const float* x = (const float*)d_in[0];
  const float* W1 = (const float*)d_in[1];
  const float* b1 = (const float*)d_in[2];
  const float* W2 = (const float*)d_in[3];
  const float* b2 = (const float*)d_in[4];
  const float* W3 = (const float*)d_in[5];
  const float* b3 = (const float*)d_in[6];

  const int B = 8192, D = 1024, H = 2048;
  char* ws = (char*)d_ws;
  short* W1t = (short*)(ws + (0ull << 20));   // [H,D] bf16   4 MB
  short* W2t = (short*)(ws + (4ull << 20));   // [H,H] bf16   8 MB
  short* W3t = (short*)(ws + (12ull << 20));  // [D,H] bf16   4 MB
  short* ybf = (short*)(ws + (16ull << 20));  // [B,D] bf16  16 MB
  short* h1 = (short*)(ws + (32ull << 20));   // [B,H] bf16  32 MB
  short* h2 = (short*)(ws + (64ull << 20));   // [B,H] bf16  32 MB
  float* acc = (float*)(ws + (96ull << 20));  // [B,D] f32   32 MB
  float* y = (float*)(ws + (128ull << 20));   // [B,D] f32   32 MB
  float* out = (float*)d_out;

  transpose_bf16<<<dim3(H / 32, D / 32), 256, 0, stream>>>(W1, W1t, D, H);
  transpose_bf16<<<dim3(H / 32, H / 32), 256, 0, stream>>>(W2, W2t, H, H);
  transpose_bf16<<<dim3(D / 32, H / 32), 256, 0, stream>>>(W3, W3t, H, D);
  init_y_kernel<<<(B * D / 4 + 255) / 256, 256, 0, stream>>>(x, y, ybf,
                                                             B * D / 4);

  const dim3 g12(H / 256, B / 256);  // (8, 32) = 256 blocks, 1/CU
  const dim3 g3(D / BN, B / BM);     // (4, 64) = 256 blocks

  // Kutta RK3, single step h=1: stages mode 1, 2, 3.
  for (int stg = 1; stg <= 3; ++stg) {
    gemm256<1024><<<g12, 512, 0, stream>>>(ybf, W1t, b1, h1, H);
    gemm256<2048><<<g12, 512, 0, stream>>>(h1, W2t, b2, h2, H);
    if (stg == 1)
      gemm8p<2048, 1><<<g3, 512, 0, stream>>>(h2, W3t, b3, nullptr, acc, y,
                                              nullptr, ybf, D);
    else if (stg == 2)
      gemm8p<2048, 2><<<g3, 512, 0, stream>>>(h2, W3t, b3, nullptr, acc, y,
                                              nullptr, ybf, D);
    else
      gemm8p<2048, 3><<<g3, 512, 0, stream>>>(h2, W3t, b3, nullptr, acc, y,
                                              out, ybf, D);
  }
}